// Round 21
// baseline (72.916 us; speedup 1.0000x reference)
//
#include <hip/hip_runtime.h>
#include <hip/hip_bf16.h>
#include <hip/hip_fp16.h>

#define N_  4
#define C_  64
#define H_  28
#define W_  60
#define ZC_ 200
#define YC_ 8
#define XC_ 200
#define OUTC_ 128
#define KD_ 512            // C_*YC_
#define EPS_ 1e-6f
#define ZB 4               // z slices per block
#define XB 8               // x positions per block
#define NCOL 32            // ZB*XB columns per block
#define NPTS 40000         // ZC_*XC_
#define TPB_GEMM 4

typedef __attribute__((ext_vector_type(8))) _Float16 half8;
typedef __attribute__((ext_vector_type(4))) float f32x4;
typedef __attribute__((ext_vector_type(4))) unsigned int u32x4;

// ---------------------------------------------------------------------------
// Prep: featH[n][h][w][c] = f16(img[n][c][h][w])  (channels-last, f16)
//       WbH[o][y*64+c]    = f16(W[o][c*8+y])      (y-major k, f16)
// ---------------------------------------------------------------------------
__global__ void gsvt_prep(const float* __restrict__ img,
                          const float* __restrict__ Wc,
                          __half* __restrict__ featH,
                          __half* __restrict__ WbH) {
    int tid = blockIdx.x * blockDim.x + threadIdx.x;
    int stride = gridDim.x * blockDim.x;
    const int totF = N_ * H_ * W_ * C_;       // 430080
    for (int i = tid; i < totF; i += stride) {
        int c  = i & 63;
        int hw = i >> 6;
        int w  = hw % W_;
        int nh = hw / W_;
        int h  = nh % H_;
        int n  = nh / H_;
        featH[i] = __float2half(img[((n * C_ + c) * H_ + h) * W_ + w]);
    }
    const int totW = OUTC_ * KD_;             // 65536
    for (int i = tid; i < totW; i += stride) {
        int k = i & (KD_ - 1);
        int o = i >> 9;
        int y = k >> 6;
        int c = k & 63;
        WbH[i] = __float2half(Wc[o * KD_ + c * YC_ + y]);
    }
}

// f16 accumulate of one corner (8 channels in u32x4), broadcast weight wp.
__device__ __forceinline__ void accq(__half2* n, const u32x4 V, const unsigned wp) {
    const __half2 w2 = *(const __half2*)&wp;
    unsigned vx = V.x, vy = V.y, vz = V.z, vw = V.w;
    n[0] = __hfma2(w2, *(const __half2*)&vx, n[0]);
    n[1] = __hfma2(w2, *(const __half2*)&vy, n[1]);
    n[2] = __hfma2(w2, *(const __half2*)&vz, n[2]);
    n[3] = __hfma2(w2, *(const __half2*)&vw, n[3]);
}

// replicated f16 pair from a float (1 cvt_pkrtz instruction)
__device__ __forceinline__ unsigned reph(float f) {
    auto h = __builtin_amdgcn_cvt_pkrtz(f, f);
    unsigned u;
    __builtin_memcpy(&u, &h, 4);
    return u;
}

// shared phase0: fill tab2 (8B unorm12 entries).  Caller provides LDS.
__device__ __forceinline__ void phase0_tab(const float* __restrict__ coords,
                                           const float* __restrict__ validm,
                                           uint2* tab2, float (*ms)[4],
                                           int z0, int x0, int t) {
    const int p0   = t;
    const int y0_  = t >> 5;
    const int col0 = t & 31;
    const int zg   = z0 + (col0 >> 3);
    const int xg   = x0 + (col0 & 7);

    float gx[4], gy[4], gzv[4], mm[4];
    #pragma unroll
    for (int cam = 0; cam < N_; ++cam) {
        const int cb = ((cam * ZC_ + zg) * YC_ + y0_) * XC_ + xg;
        gx[cam]  = coords[cb * 3 + 0];
        gy[cam]  = coords[cb * 3 + 1];
        gzv[cam] = coords[cb * 3 + 2];
        mm[cam]  = validm[cb];
        ms[p0][cam] = mm[cam];
    }
    __syncthreads();

    const float inv = 1.0f / (ms[p0][0] + ms[p0][1] + ms[p0][2] + ms[p0][3] + EPS_);
    #pragma unroll
    for (int cam = 0; cam < N_; ++cam) {
        const float xf = ((gx[cam] + 1.0f) * (float)W_ - 1.0f) * 0.5f;
        const float yf = ((gy[cam] + 1.0f) * (float)H_ - 1.0f) * 0.5f;
        const float zf = gzv[cam] * 0.5f;
        const float x0f = floorf(xf), y0f = floorf(yf), z0f = floorf(zf);
        const float wx = xf - x0f, wy = yf - y0f, wz = zf - z0f;
        const int xi = (int)x0f, yi = (int)y0f, zi = (int)z0f;

        const float zw = (zi == 0) ? (1.f - wz) : ((zi == -1) ? wz : 0.f);
        const float s  = mm[cam] * zw * inv;

        const float wx0 = (xi >= 0 && xi < W_)         ? (1.f - wx) * s : 0.f;
        const float wx1 = (xi + 1 >= 0 && xi + 1 < W_) ? wx * s         : 0.f;
        const float wy0 = (yi >= 0 && yi < H_)         ? (1.f - wy)     : 0.f;
        const float wy1 = (yi + 1 >= 0 && yi + 1 < H_) ? wy             : 0.f;

        const unsigned q00 = (unsigned)(wy0 * wx0 * 4095.f + 0.5f);
        const unsigned q01 = (unsigned)(wy0 * wx1 * 4095.f + 0.5f);
        const unsigned q10 = (unsigned)(wy1 * wx0 * 4095.f + 0.5f);
        const unsigned q11 = (unsigned)(wy1 * wx1 * 4095.f + 0.5f);

        const int xc0 = min(max(xi, 0), W_ - 1);
        const int xc1 = min(max(xi + 1, 0), W_ - 1);
        const int yc0 = min(max(yi, 0), H_ - 1);
        const int yc1 = min(max(yi + 1, 0), H_ - 1);
        const unsigned pixidx = (unsigned)((cam * H_ + yc0) * W_ + xc0);  // <6720
        const unsigned fdx = (unsigned)(xc1 - xc0);   // 0/1
        const unsigned fdy = (unsigned)(yc1 - yc0);   // 0/1

        const unsigned A = q00 | (q01 << 12) | ((q10 & 0xFFu) << 24);
        const unsigned B = (q10 >> 8) | (q11 << 4) | (pixidx << 16)
                         | (fdx << 29) | (fdy << 30);
        tab2[cam * 256 + p0] = make_uint2(A, B);
    }
    __syncthreads();
}

#define GATHER_BODY(P_, OUTSTMT)                                               \
    {                                                                          \
        const uint2 T0 = tab2[0 * 256 + (P_)];                                 \
        const uint2 T1 = tab2[1 * 256 + (P_)];                                 \
        const uint2 T2 = tab2[2 * 256 + (P_)];                                 \
        const uint2 T3 = tab2[3 * 256 + (P_)];                                 \
        u32x4 V00, V01, V02, V03, V10, V11, V12, V13;                          \
        u32x4 V20, V21, V22, V23, V30, V31, V32, V33;                          \
        ADDR_ISSUE(T0, V00, V01, V02, V03)                                     \
        ADDR_ISSUE(T1, V10, V11, V12, V13)                                     \
        ADDR_ISSUE(T2, V20, V21, V22, V23)                                     \
        ADDR_ISSUE(T3, V30, V31, V32, V33)                                     \
        __half2 zz2 = __half2half2(__ushort_as_half(0));                       \
        __half2 num[4] = {zz2, zz2, zz2, zz2};                                 \
        { DECW(T0, a, b, c, d) WAITV(12);                                      \
          accq(num, V00, a); accq(num, V01, b);                                \
          accq(num, V02, c); accq(num, V03, d); }                              \
        { DECW(T1, a, b, c, d) WAITV(8);                                       \
          accq(num, V10, a); accq(num, V11, b);                                \
          accq(num, V12, c); accq(num, V13, d); }                              \
        { DECW(T2, a, b, c, d) WAITV(4);                                       \
          accq(num, V20, a); accq(num, V21, b);                                \
          accq(num, V22, c); accq(num, V23, d); }                              \
        { DECW(T3, a, b, c, d) WAITV(0);                                       \
          accq(num, V30, a); accq(num, V31, b);                                \
          accq(num, V32, c); accq(num, V33, d); }                              \
        unsigned n0 = *(unsigned*)&num[0], n1 = *(unsigned*)&num[1];           \
        unsigned n2 = *(unsigned*)&num[2], n3 = *(unsigned*)&num[3];           \
        OUTSTMT;                                                               \
    }

#define ADDR_ISSUE(Tv, Va, Vb, Vc, Vd)                                         \
    {                                                                          \
        const bool act = (Tv.x | (Tv.y & 0xFFFFu)) != 0u;                      \
        const unsigned base = act ? ((((Tv.y >> 16) & 0x1FFFu) << 7) + lb) : lb; \
        const unsigned dxo  = act ? (((Tv.y >> 29) & 1u) << 7) : 0u;           \
        const unsigned dyo  = act ? (((Tv.y >> 30) & 1u) * (unsigned)(W_ * 128)) : 0u; \
        ISSUE(Va, fb + base);                                                  \
        ISSUE(Vb, fb + (base + dxo));                                          \
        ISSUE(Vc, fb + (base + dyo));                                          \
        ISSUE(Vd, fb + (base + dyo + dxo));                                    \
    }
#define ISSUE(V, A_) asm volatile("global_load_dwordx4 %0, %1, off" \
                                  : "=v"(V) : "v"(A_))
#define WAITV(n) do { asm volatile("s_waitcnt vmcnt(" #n ")"); \
                      __builtin_amdgcn_sched_barrier(0); } while (0)
#define DECW(Tv, w00, w01, w10, w11)                                           \
    const unsigned w00 = reph((float)(Tv.x & 0xFFFu)            * (1.f/4095.f)); \
    const unsigned w01 = reph((float)((Tv.x >> 12) & 0xFFFu)    * (1.f/4095.f)); \
    const unsigned w10 = reph((float)((Tv.x >> 24) | ((Tv.y & 0xFu) << 8)) * (1.f/4095.f)); \
    const unsigned w11 = reph((float)((Tv.y >> 4) & 0xFFFu)     * (1.f/4095.f));

// ===========================================================================
// SPLIT kernel 1: lean sampler.  LDS 12 KB -> 6 blocks/CU; writes red f16
// [64][NPTS][8] straight to global.  Grid (25, 50), block 256.
// ===========================================================================
__global__ __launch_bounds__(256, 6) void gsvt_sampleH(
        const float* __restrict__ coords,
        const float* __restrict__ validm,
        const __half* __restrict__ featH,
        __half* __restrict__ red)
{
    __shared__ uint2 tab2[N_ * 256];             // 8 KB
    __shared__ float ms[256][4];                 // 4 KB

    const int z0 = blockIdx.y * ZB;
    const int x0 = blockIdx.x * XB;
    const int t  = threadIdx.x;

    phase0_tab(coords, validm, tab2, ms, z0, x0, t);

    const int grp   = t >> 3;        // column 0..31
    const int lane8 = t & 7;
    const unsigned lb = (unsigned)(lane8 << 4);
    const char* fb = (const char*)featH;
    const int pt0 = (z0 + (grp >> 3)) * XC_ + x0 + (grp & 7);  // global point

    #pragma unroll
    for (int y = 0; y < YC_; ++y) {
        const int p  = y * 32 + grp;
        const int kb = y * 8 + lane8;
        GATHER_BODY(p,
            *(uint4*)(red + ((size_t)kb * NPTS + pt0) * 8) =
                make_uint4(n0, n1, n2, n3))
    }
}

// ===========================================================================
// SPLIT kernel 2: C[128,NPTS] = WbH[128,512]*red[512,NPTS] + bias (f16 MFMA)
// A register-resident per wave.  Grid 625 x 256.
// ===========================================================================
__global__ __launch_bounds__(256, 2) void gsvt_gemmH(
        const __half* __restrict__ red,    // [64][NPTS][8]
        const __half* __restrict__ WbH,    // [128][512]
        const float* __restrict__ bias,
        float* __restrict__ out)           // [128][NPTS]
{
    const int t    = threadIdx.x;
    const int wave = t >> 6;
    const int lane = t & 63;
    const int q    = lane >> 4;
    const int l16  = lane & 15;

    half8 A0[16], A1[16];
    const __half* wrow0 = WbH + (wave * 32 + l16) * KD_;
    #pragma unroll
    for (int ks = 0; ks < 16; ++ks) {
        A0[ks] = *(const half8*)(wrow0 + ks * 32 + q * 8);
        A1[ks] = *(const half8*)(wrow0 + 16 * KD_ + ks * 32 + q * 8);
    }
    float bs0[4], bs1[4];
    #pragma unroll
    for (int j = 0; j < 4; ++j) {
        bs0[j] = bias[wave * 32 + q * 4 + j];
        bs1[j] = bias[wave * 32 + q * 4 + j + 16];
    }

    for (int tt = 0; tt < TPB_GEMM; ++tt) {
        const int n0 = (blockIdx.x * TPB_GEMM + tt) * 16;

        half8 Bf[16];
        #pragma unroll
        for (int ks = 0; ks < 16; ++ks) {
            const int kb = ks * 4 + q;
            Bf[ks] = *(const half8*)(red + ((size_t)kb * NPTS + n0 + l16) * 8);
        }

        f32x4 acc0 = {0.f,0.f,0.f,0.f};
        f32x4 acc1 = {0.f,0.f,0.f,0.f};
        #pragma unroll
        for (int ks = 0; ks < 16; ++ks) {
            acc0 = __builtin_amdgcn_mfma_f32_16x16x32_f16(A0[ks], Bf[ks], acc0, 0, 0, 0);
            acc1 = __builtin_amdgcn_mfma_f32_16x16x32_f16(A1[ks], Bf[ks], acc1, 0, 0, 0);
        }

        #pragma unroll
        for (int j = 0; j < 4; ++j) {
            const int o0 = wave * 32 + q * 4 + j;
            out[(size_t)o0 * NPTS + n0 + l16] = acc0[j] + bs0[j];
            out[(size_t)(o0 + 16) * NPTS + n0 + l16] = acc1[j] + bs1[j];
        }
    }
}

// ===========================================================================
// FALLBACK: R20 fused kernel (ws too small for red)
// ===========================================================================
__global__ __launch_bounds__(256, 4) void gsvt_fusedG(
        const float* __restrict__ coords,
        const float* __restrict__ validm,
        const __half* __restrict__ featH,
        const __half* __restrict__ WbH,
        const float* __restrict__ bias,
        float* __restrict__ out)
{
    __shared__ uint2 tab2[N_ * 256];             // 8 KB
    __shared__ unsigned short redB[64][NCOL][8]; // 32 KB
    float (*ms)[4] = (float(*)[4])&redB[0][0][0];

    const int z0 = blockIdx.y * ZB;
    const int x0 = blockIdx.x * XB;
    const int t  = threadIdx.x;

    phase0_tab(coords, validm, tab2, ms, z0, x0, t);

    const int grp   = t >> 3;
    const int lane8 = t & 7;
    const unsigned lb = (unsigned)(lane8 << 4);
    const char* fb = (const char*)featH;

    #pragma unroll
    for (int y = 0; y < YC_; ++y) {
        const int p    = y * 32 + grp;
        const int kb   = y * 8 + lane8;
        const int pcol = (grp & 16) | ((grp ^ kb) & 15);
        GATHER_BODY(p,
            *(uint4*)&redB[kb][pcol][0] = make_uint4(n0, n1, n2, n3))
    }
    __syncthreads();

    const int wave = t >> 6;
    const int lane = t & 63;
    const int q    = lane >> 4;
    const int l16  = lane & 15;

    f32x4 acc00 = {0.f,0.f,0.f,0.f}, acc01 = {0.f,0.f,0.f,0.f};
    f32x4 acc10 = {0.f,0.f,0.f,0.f}, acc11 = {0.f,0.f,0.f,0.f};
    const __half* wbase = WbH + (wave * 32 + l16) * KD_;

    #pragma unroll
    for (int ks = 0; ks < 16; ++ks) {
        const int kb = ks * 4 + q;
        const int xs = l16 ^ (kb & 15);
        const half8 Bf0 = *(const half8*)&redB[kb][xs][0];
        const half8 Bf1 = *(const half8*)&redB[kb][16 + xs][0];
        const half8 Af0 = *(const half8*)(wbase + ks * 32 + q * 8);
        const half8 Af1 = *(const half8*)(wbase + 16 * KD_ + ks * 32 + q * 8);
        acc00 = __builtin_amdgcn_mfma_f32_16x16x32_f16(Af0, Bf0, acc00, 0, 0, 0);
        acc01 = __builtin_amdgcn_mfma_f32_16x16x32_f16(Af0, Bf1, acc01, 0, 0, 0);
        acc10 = __builtin_amdgcn_mfma_f32_16x16x32_f16(Af1, Bf0, acc10, 0, 0, 0);
        acc11 = __builtin_amdgcn_mfma_f32_16x16x32_f16(Af1, Bf1, acc11, 0, 0, 0);
    }

    #pragma unroll
    for (int ct = 0; ct < 2; ++ct) {
        const int c2  = ct * 16 + l16;
        const int zz  = c2 >> 3;
        const int xl  = c2 & 7;
        const int ob  = (z0 + zz) * XC_ + x0 + xl;
        const f32x4 a0 = ct ? acc01 : acc00;
        const f32x4 a1 = ct ? acc11 : acc10;
        #pragma unroll
        for (int j = 0; j < 4; ++j) {
            const int o0 = wave * 32 + q * 4 + j;
            out[o0 * (ZC_ * XC_) + ob] = a0[j] + bias[o0];
            const int o1 = o0 + 16;
            out[o1 * (ZC_ * XC_) + ob] = a1[j] + bias[o1];
        }
    }
}

extern "C" void kernel_launch(void* const* d_in, const int* in_sizes, int n_in,
                              void* d_out, int out_size, void* d_ws, size_t ws_size,
                              hipStream_t stream) {
    const float* coords = (const float*)d_in[0];   // (1,4,200,8,200,3)
    const float* validm = (const float*)d_in[1];   // (1,4,200,8,200,1)
    const float* img    = (const float*)d_in[2];   // (1,4,64,28,60)
    const float* Wc     = (const float*)d_in[3];   // (128, 512)
    const float* bias   = (const float*)d_in[4];   // (128)
    float* out = (float*)d_out;                    // (1,1,128,200,200)

    __half* featH = (__half*)d_ws;                 // 430080 f16
    __half* WbH   = featH + (N_ * H_ * W_ * C_);   // 65536 f16
    __half* red   = WbH + (OUTC_ * KD_);           // 64*40000*8 f16 = 41 MB

    const size_t need = (size_t)(N_ * H_ * W_ * C_ + OUTC_ * KD_) * 2
                      + (size_t)64 * NPTS * 8 * 2;

    gsvt_prep<<<512, 256, 0, stream>>>(img, Wc, featH, WbH);

    dim3 grid(XC_ / XB, ZC_ / ZB);   // (25, 50)
    if (ws_size >= need) {
        gsvt_sampleH<<<grid, 256, 0, stream>>>(coords, validm, featH, red);
        gsvt_gemmH<<<625, 256, 0, stream>>>(red, WbH, bias, out);
    } else {
        gsvt_fusedG<<<grid, 256, 0, stream>>>(coords, validm, featH, WbH, bias, out);
    }
}

// Round 22
// 55.134 us; speedup vs baseline: 1.3225x; 1.3225x over previous
//
#include <hip/hip_runtime.h>
#include <hip/hip_bf16.h>
#include <hip/hip_fp16.h>

#define N_  4
#define C_  64
#define H_  28
#define W_  60
#define ZC_ 200
#define YC_ 8
#define XC_ 200
#define OUTC_ 128
#define KD_ 512            // C_*YC_
#define EPS_ 1e-6f
#define ZB 4               // z slices per block
#define XB 8               // x positions per block
#define NCOL 32            // ZB*XB columns per block

typedef __attribute__((ext_vector_type(8))) _Float16 half8;
typedef __attribute__((ext_vector_type(4))) float f32x4;
typedef __attribute__((ext_vector_type(4))) unsigned int u32x4;

// ---------------------------------------------------------------------------
// Prep: featH[n][h][w][c] = f16(img[n][c][h][w])  (channels-last, f16)
//       WbH[o][y*64+c]    = f16(W[o][c*8+y])      (y-major k, f16)
// ---------------------------------------------------------------------------
__global__ void gsvt_prep(const float* __restrict__ img,
                          const float* __restrict__ Wc,
                          __half* __restrict__ featH,
                          __half* __restrict__ WbH) {
    int tid = blockIdx.x * blockDim.x + threadIdx.x;
    int stride = gridDim.x * blockDim.x;
    const int totF = N_ * H_ * W_ * C_;       // 430080
    for (int i = tid; i < totF; i += stride) {
        int c  = i & 63;
        int hw = i >> 6;
        int w  = hw % W_;
        int nh = hw / W_;
        int h  = nh % H_;
        int n  = nh / H_;
        featH[i] = __float2half(img[((n * C_ + c) * H_ + h) * W_ + w]);
    }
    const int totW = OUTC_ * KD_;             // 65536
    for (int i = tid; i < totW; i += stride) {
        int k = i & (KD_ - 1);
        int o = i >> 9;
        int y = k >> 6;
        int c = k & 63;
        WbH[i] = __float2half(Wc[o * KD_ + c * YC_ + y]);
    }
}

// f16 accumulate of one corner (8 channels in u32x4), broadcast weight wp.
__device__ __forceinline__ void accq(__half2* n, const u32x4 V, const unsigned wp) {
    const __half2 w2 = *(const __half2*)&wp;
    unsigned vx = V.x, vy = V.y, vz = V.z, vw = V.w;
    n[0] = __hfma2(w2, *(const __half2*)&vx, n[0]);
    n[1] = __hfma2(w2, *(const __half2*)&vy, n[1]);
    n[2] = __hfma2(w2, *(const __half2*)&vz, n[2]);
    n[3] = __hfma2(w2, *(const __half2*)&vw, n[3]);
}

// ===========================================================================
// Fused: phase0 (f16-weight tables) -> asm-batched gather (16 loads in
// flight, counted vmcnt) with hfma2 accumulation -> in-block f16 GEMM
// C[128,32] = WbH[128,512] * redB[512,32].
// Grid: (25, 50), block 256.  LDS = 48 KB -> 3 blocks/CU.
// Best-measured configuration (R16): 54.98 us total.
// ===========================================================================
__global__ __launch_bounds__(256, 3) void gsvt_fusedF(
        const float* __restrict__ coords,        // (N, ZC, YC, XC, 3)
        const float* __restrict__ validm,        // (N, ZC, YC, XC)
        const __half* __restrict__ featH,        // (N, H, W, C) f16
        const __half* __restrict__ WbH,          // (OUTC, 512) f16, y-major k
        const float* __restrict__ bias,          // (OUTC)
        float* __restrict__ out)                 // (OUTC, ZC, XC)
{
    // tab entry (16B): x = w00|w01 (f16x2), y = w10|w11 (f16x2),
    //                  z = base byte offset, w = dxo | dyo<<16
    __shared__ uint4 tab[N_ * 256];              // 16 KB
    __shared__ unsigned short redB[64][NCOL][8]; // 32 KB (f16 payload)
    float (*ms)[4] = (float(*)[4])&redB[0][0][0];  // 4 KB alias (dead before redB)

    const int z0 = blockIdx.y * ZB;
    const int x0 = blockIdx.x * XB;
    const int t  = threadIdx.x;

    // ---- phase 0a: one pair per thread; p0 = y*32 + col, col = zz*8+xl ----
    const int p0   = t;
    const int y0_  = t >> 5;
    const int col0 = t & 31;
    const int zg   = z0 + (col0 >> 3);
    const int xg   = x0 + (col0 & 7);

    float gx[4], gy[4], gzv[4], mm[4];
    #pragma unroll
    for (int cam = 0; cam < N_; ++cam) {
        const int cb = ((cam * ZC_ + zg) * YC_ + y0_) * XC_ + xg;
        gx[cam]  = coords[cb * 3 + 0];
        gy[cam]  = coords[cb * 3 + 1];
        gzv[cam] = coords[cb * 3 + 2];
        mm[cam]  = validm[cb];
        ms[p0][cam] = mm[cam];
    }
    __syncthreads();

    // ---- phase 0b: f16 corner weights (mask, zw, 1/den folded) + offsets ----
    {
        const float inv = 1.0f / (ms[p0][0] + ms[p0][1] + ms[p0][2] + ms[p0][3] + EPS_);
        #pragma unroll
        for (int cam = 0; cam < N_; ++cam) {
            const float xf = ((gx[cam] + 1.0f) * (float)W_ - 1.0f) * 0.5f;
            const float yf = ((gy[cam] + 1.0f) * (float)H_ - 1.0f) * 0.5f;
            const float zf = gzv[cam] * 0.5f;
            const float x0f = floorf(xf), y0f = floorf(yf), z0f = floorf(zf);
            const float wx = xf - x0f, wy = yf - y0f, wz = zf - z0f;
            const int xi = (int)x0f, yi = (int)y0f, zi = (int)z0f;

            const float zw = (zi == 0) ? (1.f - wz) : ((zi == -1) ? wz : 0.f);
            const float s  = mm[cam] * zw * inv;

            const float wx0 = (xi >= 0 && xi < W_)         ? (1.f - wx) * s : 0.f;
            const float wx1 = (xi + 1 >= 0 && xi + 1 < W_) ? wx * s         : 0.f;
            const float wy0 = (yi >= 0 && yi < H_)         ? (1.f - wy)     : 0.f;
            const float wy1 = (yi + 1 >= 0 && yi + 1 < H_) ? wy             : 0.f;

            const unsigned h00 = __half_as_ushort(__float2half(wy0 * wx0));
            const unsigned h01 = __half_as_ushort(__float2half(wy0 * wx1));
            const unsigned h10 = __half_as_ushort(__float2half(wy1 * wx0));
            const unsigned h11 = __half_as_ushort(__float2half(wy1 * wx1));

            const int xc0 = min(max(xi, 0), W_ - 1);
            const int xc1 = min(max(xi + 1, 0), W_ - 1);
            const int yc0 = min(max(yi, 0), H_ - 1);
            const int yc1 = min(max(yi + 1, 0), H_ - 1);
            const unsigned base = (unsigned)((((cam * H_ + yc0) * W_) + xc0) * 128);
            const unsigned dxo  = (unsigned)((xc1 - xc0) * 128);          // 0 or 128
            const unsigned dyo  = (unsigned)((yc1 - yc0) * W_ * 128);     // 0 or 7680
            tab[cam * 256 + p0] = make_uint4(h00 | (h01 << 16), h10 | (h11 << 16),
                                             base, dxo | (dyo << 16));
        }
    }
    __syncthreads();

    // ---- sampling: 32 groups of 8 lanes; asm-batched 16-load gather ----
    const int grp   = t >> 3;        // column 0..31
    const int lane8 = t & 7;
    const unsigned lb = (unsigned)(lane8 << 4);
    const char* fb = (const char*)featH;

    #define ISSUE(V, A_) asm volatile("global_load_dwordx4 %0, %1, off" \
                                      : "=v"(V) : "v"(A_))
    #define WAITV(n) do { asm volatile("s_waitcnt vmcnt(" #n ")"); \
                          __builtin_amdgcn_sched_barrier(0); } while (0)

    #pragma unroll
    for (int y = 0; y < YC_; ++y) {
        const int p = y * 32 + grp;

        const uint4 T0 = tab[0 * 256 + p];
        const uint4 T1 = tab[1 * 256 + p];
        const uint4 T2 = tab[2 * 256 + p];
        const uint4 T3 = tab[3 * 256 + p];

        // per-cam predicated addresses (inactive -> offset 0, one hot line)
        u32x4 V00, V01, V02, V03, V10, V11, V12, V13;
        u32x4 V20, V21, V22, V23, V30, V31, V32, V33;
        #define ADDR_ISSUE(Tv, Va, Vb, Vc, Vd)                                 \
            {                                                                  \
                const bool act = (Tv.x | Tv.y) != 0u;                          \
                const unsigned base = act ? (Tv.z + lb) : lb;                  \
                const unsigned dxo  = act ? (Tv.w & 0xFFFFu) : 0u;             \
                const unsigned dyo  = act ? (Tv.w >> 16) : 0u;                 \
                ISSUE(Va, fb + base);                                          \
                ISSUE(Vb, fb + (base + dxo));                                  \
                ISSUE(Vc, fb + (base + dyo));                                  \
                ISSUE(Vd, fb + (base + dyo + dxo));                            \
            }
        ADDR_ISSUE(T0, V00, V01, V02, V03)
        ADDR_ISSUE(T1, V10, V11, V12, V13)
        ADDR_ISSUE(T2, V20, V21, V22, V23)
        ADDR_ISSUE(T3, V30, V31, V32, V33)
        #undef ADDR_ISSUE

        __half2 zz2 = __half2half2(__ushort_as_half(0));
        __half2 num[4] = {zz2, zz2, zz2, zz2};

        // broadcast helpers: wp = halfword replicated
        #define BLO(u) (((u) & 0xFFFFu) | ((u) << 16))
        #define BHI(u) (((u) & 0xFFFF0000u) | ((u) >> 16))

        WAITV(12);
        accq(num, V00, BLO(T0.x)); accq(num, V01, BHI(T0.x));
        accq(num, V02, BLO(T0.y)); accq(num, V03, BHI(T0.y));
        WAITV(8);
        accq(num, V10, BLO(T1.x)); accq(num, V11, BHI(T1.x));
        accq(num, V12, BLO(T1.y)); accq(num, V13, BHI(T1.y));
        WAITV(4);
        accq(num, V20, BLO(T2.x)); accq(num, V21, BHI(T2.x));
        accq(num, V22, BLO(T2.y)); accq(num, V23, BHI(T2.y));
        WAITV(0);
        accq(num, V30, BLO(T3.x)); accq(num, V31, BHI(T3.x));
        accq(num, V32, BLO(T3.y)); accq(num, V33, BHI(T3.y));
        #undef BLO
        #undef BHI

        const int kb   = y * 8 + lane8;
        const int pcol = (grp & 16) | ((grp ^ kb) & 15);   // XOR swizzle
        *(uint4*)&redB[kb][pcol][0] =
            make_uint4(*(unsigned*)&num[0], *(unsigned*)&num[1],
                       *(unsigned*)&num[2], *(unsigned*)&num[3]);
    }
    #undef ISSUE
    #undef WAITV
    __syncthreads();

    // ---- GEMM: C[128,32] = WbH[128,512] * redB[512,32]  (f16 MFMA) ----
    const int wave = t >> 6;        // rows [wave*32, +32)
    const int lane = t & 63;
    const int q    = lane >> 4;
    const int l16  = lane & 15;

    f32x4 acc00 = {0.f,0.f,0.f,0.f}, acc01 = {0.f,0.f,0.f,0.f};
    f32x4 acc10 = {0.f,0.f,0.f,0.f}, acc11 = {0.f,0.f,0.f,0.f};
    const __half* wbase = WbH + (wave * 32 + l16) * KD_;

    #pragma unroll
    for (int ks = 0; ks < 16; ++ks) {
        const int kb = ks * 4 + q;
        const int xs = l16 ^ (kb & 15);
        const half8 Bf0 = *(const half8*)&redB[kb][xs][0];
        const half8 Bf1 = *(const half8*)&redB[kb][16 + xs][0];
        const half8 Af0 = *(const half8*)(wbase + ks * 32 + q * 8);
        const half8 Af1 = *(const half8*)(wbase + 16 * KD_ + ks * 32 + q * 8);
        acc00 = __builtin_amdgcn_mfma_f32_16x16x32_f16(Af0, Bf0, acc00, 0, 0, 0);
        acc01 = __builtin_amdgcn_mfma_f32_16x16x32_f16(Af0, Bf1, acc01, 0, 0, 0);
        acc10 = __builtin_amdgcn_mfma_f32_16x16x32_f16(Af1, Bf0, acc10, 0, 0, 0);
        acc11 = __builtin_amdgcn_mfma_f32_16x16x32_f16(Af1, Bf1, acc11, 0, 0, 0);
    }

    #pragma unroll
    for (int ct = 0; ct < 2; ++ct) {
        const int c2  = ct * 16 + l16;
        const int zz  = c2 >> 3;
        const int xl  = c2 & 7;
        const int ob  = (z0 + zz) * XC_ + x0 + xl;
        const f32x4 a0 = ct ? acc01 : acc00;
        const f32x4 a1 = ct ? acc11 : acc10;
        #pragma unroll
        for (int j = 0; j < 4; ++j) {
            const int o0 = wave * 32 + q * 4 + j;
            out[o0 * (ZC_ * XC_) + ob] = a0[j] + bias[o0];
            const int o1 = o0 + 16;
            out[o1 * (ZC_ * XC_) + ob] = a1[j] + bias[o1];
        }
    }
}

extern "C" void kernel_launch(void* const* d_in, const int* in_sizes, int n_in,
                              void* d_out, int out_size, void* d_ws, size_t ws_size,
                              hipStream_t stream) {
    const float* coords = (const float*)d_in[0];   // (1,4,200,8,200,3)
    const float* validm = (const float*)d_in[1];   // (1,4,200,8,200,1)
    const float* img    = (const float*)d_in[2];   // (1,4,64,28,60)
    const float* Wc     = (const float*)d_in[3];   // (128, 512)
    const float* bias   = (const float*)d_in[4];   // (128)
    float* out = (float*)d_out;                    // (1,1,128,200,200)

    __half* featH = (__half*)d_ws;                 // 430080 f16
    __half* WbH   = featH + (N_ * H_ * W_ * C_);   // 65536 f16

    gsvt_prep<<<512, 256, 0, stream>>>(img, Wc, featH, WbH);

    dim3 grid(XC_ / XB, ZC_ / ZB);   // (25, 50)
    gsvt_fusedF<<<grid, 256, 0, stream>>>(coords, validm, featH, WbH, bias, out);
}